// Round 5
// baseline (186.668 us; speedup 1.0000x reference)
//
#include <hip/hip_runtime.h>
#include <hip/hip_cooperative_groups.h>

namespace cg = cooperative_groups;

#define EPSF 0.01f
#define THREADS 256
#define EPT 128                  // elements per thread
#define CHUNK (THREADS * EPT)    // 32768 elements per block
#define NWORDS (EPT / 8)         // 16 packed 4-bit code words per thread

typedef unsigned long long u64;
typedef unsigned int u32;

// Per-category change scalars, exactly as the reference computes them.
// jnp.clip(x, lo, hi) == min(max(x, lo), hi)
__device__ __forceinline__ void load_changes(const float* bd, const float* de,
                                             const float* sa, const float* in,
                                             const float* bi, float ch[5]) {
    float vbd = *bd, vd = *de, vs = *sa, vi = *in, vbi = *bi;
    ch[0] = fminf(vbd, fminf(0.0f, vd) - EPSF);
    ch[1] = fminf(fmaxf(vd, vbd + EPSF), 0.0f - EPSF);
    ch[2] = fminf(fmaxf(vs, vd + EPSF), vi - EPSF);
    ch[3] = fminf(fmaxf(vi, 0.0f + EPSF), vbi - EPSF);
    ch[4] = fmaxf(vbi, fmaxf(0.0f, vi) + EPSF);
}

// code 0..4 -> change; cmp+cndmask chain (no runtime-indexed array -> no scratch)
__device__ __forceinline__ float selc(u32 v, float c0, float c1, float c2,
                                      float c3, float c4) {
    return (v == 0) ? c0 : (v == 1) ? c1 : (v == 2) ? c2 : (v == 3) ? c3 : c4;
}

// One cooperative kernel:
//  Phase 1: read ann once; codes stay in REGISTERS; exact per-block counts->bcT.
//  grid.sync()
//  Phase 2: each block redundantly sums predecessor counts (20 KB, L2-resident,
//  fully parallel -- no cross-block serialization), derives its exact float
//  base, then decodes from registers and emits exclusive prefixes (aligned
//  float4 stores; out[0]=origin falls out naturally).
__global__ __launch_bounds__(THREADS, 4) void k_fused(
    const int* __restrict__ ann, int* __restrict__ bcT, float* __restrict__ out,
    long long n, int nb, const float* org, const float* bd, const float* de,
    const float* sa, const float* in, const float* bi) {
    float ch[5];
    load_changes(bd, de, sa, in, bi, ch);
    const float c0 = ch[0], c1 = ch[1], c2 = ch[2], c3 = ch[3], c4 = ch[4];

    __shared__ int sred[THREADS / 64][5];
    __shared__ float wsum[THREADS / 64];
    __shared__ float s_base;

    const int tid = threadIdx.x, lane = tid & 63, wv = tid >> 6;
    const int vbid = blockIdx.x;
    const long long start = (long long)vbid * CHUNK;
    const long long i0 = start + (long long)tid * EPT;
    const bool full = (start + CHUNK <= n);

    // ---- Phase 1: load + pack codes (registers) + packed 12-bit counts
    u32 cw[NWORDS];
#pragma unroll
    for (int k = 0; k < NWORDS; ++k) cw[k] = 0;
    u64 pk = 0ull;

    if (full) {
        const int4* p = reinterpret_cast<const int4*>(ann + i0);
#pragma unroll
        for (int k = 0; k < EPT / 4; ++k) {
            int4 a = p[k];
            u32 cx = (u32)(a.x - 1), cy = (u32)(a.y - 1);
            u32 cz = (u32)(a.z - 1), cd = (u32)(a.w - 1);
            pk += (1ull << (cx * 12)) + (1ull << (cy * 12)) +
                  (1ull << (cz * 12)) + (1ull << (cd * 12));
            cw[k >> 1] |= (cx | (cy << 4) | (cz << 8) | (cd << 12))
                          << ((k & 1) * 16);
        }
    } else {
#pragma unroll
        for (int j = 0; j < EPT; ++j) {
            long long i = i0 + j;
            if (i < n) {
                u32 c = (u32)(ann[i] - 1);
                pk += (1ull << (c * 12));
                cw[j >> 3] |= c << ((j & 7) * 4);
            }
        }
    }

    int cnt[5];
#pragma unroll
    for (int c = 0; c < 5; ++c) cnt[c] = (int)((pk >> (c * 12)) & 0xFFFull);
    // per-thread sum of its EPT changes (exact counts x change values)
    float lsum = (float)cnt[0] * c0 + (float)cnt[1] * c1 + (float)cnt[2] * c2 +
                 (float)cnt[3] * c3 + (float)cnt[4] * c4;

    // wave-inclusive scan of lsum for intra-block offsets
    float x = lsum;
#pragma unroll
    for (int off = 1; off < 64; off <<= 1) {
        float y = __shfl_up(x, off, 64);
        if (lane >= off) x += y;
    }
    if (lane == 63) wsum[wv] = x;

    // wave-reduce integer counts -> block counts
#pragma unroll
    for (int c = 0; c < 5; ++c) {
        int s = cnt[c];
#pragma unroll
        for (int off = 32; off > 0; off >>= 1) s += __shfl_down(s, off, 64);
        if (lane == 0) sred[wv][c] = s;
    }
    __syncthreads();
    if (tid == 0) {
#pragma unroll
        for (int c = 0; c < 5; ++c)
            bcT[c * nb + vbid] =
                sred[0][c] + sred[1][c] + sred[2][c] + sred[3][c];
    }

    cg::this_grid().sync();

    // ---- Phase 2a: exact exclusive base from predecessor counts (L2 reads)
    int pc[5];
#pragma unroll
    for (int c = 0; c < 5; ++c) {
        int s = 0;
        for (int j = tid; j < vbid; j += THREADS) s += bcT[c * nb + j];
#pragma unroll
        for (int off = 32; off > 0; off >>= 1) s += __shfl_down(s, off, 64);
        pc[c] = s;
    }
    if (lane == 0) {
#pragma unroll
        for (int c = 0; c < 5; ++c) sred[wv][c] = pc[c];
    }
    __syncthreads();
    if (tid == 0) {
        double acc = (double)(*org);
#pragma unroll
        for (int c = 0; c < 5; ++c) {
            int tot = sred[0][c] + sred[1][c] + sred[2][c] + sred[3][c];
            acc += (double)tot * (double)ch[c];
        }
        s_base = (float)acc;
    }
    __syncthreads();

    // ---- Phase 2b: decode from registers + emit exclusive prefixes
    float w0 = wsum[0], w1 = wsum[1], w2 = wsum[2], w3 = wsum[3];
    float waveOff =
        (wv > 0 ? w0 : 0.0f) + (wv > 1 ? w1 : 0.0f) + (wv > 2 ? w2 : 0.0f);
    float acc = s_base + waveOff + (x - lsum);  // this thread's exclusive start

    if (full) {
        float4* q = reinterpret_cast<float4*>(out + i0);
#pragma unroll
        for (int g = 0; g < EPT / 4; ++g) {
            u32 w = cw[g >> 1] >> ((g & 1) * 16);  // 4 nibbles
            float4 f;
            f.x = acc;
            acc += selc(w & 0xF, c0, c1, c2, c3, c4);
            f.y = acc;
            acc += selc((w >> 4) & 0xF, c0, c1, c2, c3, c4);
            f.z = acc;
            acc += selc((w >> 8) & 0xF, c0, c1, c2, c3, c4);
            f.w = acc;
            acc += selc((w >> 12) & 0xF, c0, c1, c2, c3, c4);
            q[g] = f;
        }
    } else {
#pragma unroll
        for (int j = 0; j < EPT; ++j) {
            if (i0 + j < n) {
                out[i0 + j] = acc;
                acc += selc((cw[j >> 3] >> ((j & 7) * 4)) & 0xF, c0, c1, c2, c3,
                            c4);
            }
        }
    }

    // inclusive total at out[n], written by the last block
    if (vbid == nb - 1 && tid == 0)
        out[n] = s_base + (w0 + w1 + w2 + w3);
}

extern "C" void kernel_launch(void* const* d_in, const int* in_sizes, int n_in,
                              void* d_out, int out_size, void* d_ws, size_t ws_size,
                              hipStream_t stream) {
    const int* ann = (const int*)d_in[0];
    const float* org = (const float*)d_in[1];
    const float* bd = (const float*)d_in[2];
    const float* de = (const float*)d_in[3];
    const float* sa = (const float*)d_in[4];
    const float* in = (const float*)d_in[5];
    const float* bi = (const float*)d_in[6];
    float* out = (float*)d_out;

    long long n = (long long)in_sizes[0];
    int nb = (int)((n + CHUNK - 1) / CHUNK);  // 1024 for N=2^25
    if (nb < 1) nb = 1;

    int* bcT = (int*)d_ws;  // nb*5 ints

    void* args[] = {(void*)&ann, (void*)&bcT, (void*)&out, (void*)&n,
                    (void*)&nb,  (void*)&org, (void*)&bd,  (void*)&de,
                    (void*)&sa,  (void*)&in,  (void*)&bi};
    hipLaunchCooperativeKernel((const void*)k_fused, dim3(nb), dim3(THREADS),
                               args, 0, stream);
}

// Round 7
// 75.213 us; speedup vs baseline: 2.4818x; 2.4818x over previous
//
#include <hip/hip_runtime.h>

#define EPSF 0.01f
#define THREADS 256
#define WAVES (THREADS / 64)
#define TILE (THREADS * 4)      // 1024 elems: thread t -> 4 elems at 4*t (coalesced)
#define TPB 16                  // tiles per block -> chunk = 16384
#define CHUNK (TILE * TPB)

typedef unsigned long long u64;
typedef unsigned int u32;

// Per-category change scalars, exactly as the reference computes them.
// jnp.clip(x, lo, hi) == min(max(x, lo), hi)
__device__ __forceinline__ void load_changes(const float* bd, const float* de,
                                             const float* sa, const float* in,
                                             const float* bi, float ch[5]) {
    float vbd = *bd, vd = *de, vs = *sa, vi = *in, vbi = *bi;
    ch[0] = fminf(vbd, fminf(0.0f, vd) - EPSF);
    ch[1] = fminf(fmaxf(vd, vbd + EPSF), 0.0f - EPSF);
    ch[2] = fminf(fmaxf(vs, vd + EPSF), vi - EPSF);
    ch[3] = fminf(fmaxf(vi, 0.0f + EPSF), vbi - EPSF);
    ch[4] = fmaxf(vbi, fmaxf(0.0f, vi) + EPSF);
}

// category 1..5 -> change; cmp+cndmask chain (no runtime-indexed array).
__device__ __forceinline__ float sel_change(int v, float c0, float c1, float c2,
                                            float c3, float c4) {
    return (v == 1) ? c0 : (v == 2) ? c1 : (v == 3) ? c2 : (v == 4) ? c3 : c4;
}

// Pass 1: exact per-block category counts, fully coalesced int4 reads
// (16 B/lane, wave = 1 KB contiguous = 8 full 128B lines per instruction).
// Packed 12-bit per-thread count fields (<=64 per field). Counts transposed
// bcT[c*nb+b] so pass 2's predecessor sum coalesces.
__global__ __launch_bounds__(THREADS) void k_count(const int* __restrict__ ann,
                                                   int* __restrict__ bcT,
                                                   long long n, int nb) {
    long long start = (long long)blockIdx.x * CHUNK;
    long long end = start + CHUNK;
    if (end > n) end = n;

    u64 pk = 0ull;
    for (long long i = start + (long long)threadIdx.x * 4; i < end;
         i += (long long)THREADS * 4) {
        if (i + 4 <= end) {
            int4 a = *reinterpret_cast<const int4*>(ann + i);
            pk += (1ull << ((a.x - 1) * 12)) + (1ull << ((a.y - 1) * 12)) +
                  (1ull << ((a.z - 1) * 12)) + (1ull << ((a.w - 1) * 12));
        } else {
            for (long long j = i; j < end; ++j)
                pk += (1ull << ((ann[j] - 1) * 12));
        }
    }

    int cnt[5];
#pragma unroll
    for (int c = 0; c < 5; ++c) cnt[c] = (int)((pk >> (c * 12)) & 0xFFFull);
    const int lane = threadIdx.x & 63, wv = threadIdx.x >> 6;
#pragma unroll
    for (int c = 0; c < 5; ++c) {
        int x = cnt[c];
#pragma unroll
        for (int off = 32; off > 0; off >>= 1) x += __shfl_down(x, off, 64);
        cnt[c] = x;  // lane 0 holds wave total
    }
    __shared__ int sred[WAVES][5];
    if (lane == 0) {
#pragma unroll
        for (int c = 0; c < 5; ++c) sred[wv][c] = cnt[c];
    }
    __syncthreads();
    if (threadIdx.x == 0) {
#pragma unroll
        for (int c = 0; c < 5; ++c)
            bcT[c * nb + blockIdx.x] =
                sred[0][c] + sred[1][c] + sred[2][c] + sred[3][c];
    }
}

// Pass 2: exact float base via redundant predecessor-count sum (40 KB,
// L2-resident, fully parallel, no serialization), then per 1024-elem tile:
// coalesced int4 load -> 4-elem local prefix -> wave scan -> wave offsets via
// double-buffered wsum (1 barrier/tile) -> coalesced exclusive-prefix float4
// store. COVERAGE CHECK (the R6 bug): 256 threads x 4 elems == TILE == 1024. OK.
__global__ __launch_bounds__(THREADS) void k_emit(
    const int* __restrict__ ann, const int* __restrict__ bcT,
    float* __restrict__ out, long long n, int nb, const float* org,
    const float* bd, const float* de, const float* sa, const float* in,
    const float* bi) {
    float ch[5];
    load_changes(bd, de, sa, in, bi, ch);
    const float c0 = ch[0], c1 = ch[1], c2 = ch[2], c3 = ch[3], c4 = ch[4];

    __shared__ int sred[WAVES][5];
    __shared__ float wsum[2][WAVES];  // double-buffered: 1 barrier per tile
    __shared__ float s_base;

    const int tid = threadIdx.x, lane = tid & 63, wv = tid >> 6;
    const int vbid = blockIdx.x;

    // Phase A: base = org + sum_c (#cat_c before my chunk) * ch_c (exact ints)
    int pc[5];
#pragma unroll
    for (int c = 0; c < 5; ++c) {
        int s = 0;
        for (int j = tid; j < vbid; j += THREADS) s += bcT[c * nb + j];
#pragma unroll
        for (int off = 32; off > 0; off >>= 1) s += __shfl_down(s, off, 64);
        pc[c] = s;
    }
    if (lane == 0) {
#pragma unroll
        for (int c = 0; c < 5; ++c) sred[wv][c] = pc[c];
    }
    __syncthreads();
    if (tid == 0) {
        double acc = (double)(*org);
#pragma unroll
        for (int c = 0; c < 5; ++c) {
            int tot = sred[0][c] + sred[1][c] + sred[2][c] + sred[3][c];
            acc += (double)tot * (double)ch[c];
        }
        s_base = (float)acc;
    }
    __syncthreads();

    const long long start = (long long)vbid * CHUNK;
    long long end = start + CHUNK;
    if (end > n) end = n;
    float running = s_base;

    for (int t = 0; t < TPB; ++t) {
        long long tb = start + (long long)t * TILE;
        if (tb >= end) break;  // block-uniform
        long long i = tb + (long long)tid * 4;  // 4 elems/thread, coalesced

        float e1, e2, e3, s;
        const bool vec = (i + 4 <= n);
        if (vec) {
            int4 a = *reinterpret_cast<const int4*>(ann + i);
            float d0 = sel_change(a.x, c0, c1, c2, c3, c4);
            float d1 = sel_change(a.y, c0, c1, c2, c3, c4);
            float d2 = sel_change(a.z, c0, c1, c2, c3, c4);
            float d3 = sel_change(a.w, c0, c1, c2, c3, c4);
            e1 = d0; e2 = e1 + d1; e3 = e2 + d2; s = e3 + d3;
        } else {
            float e[5];
            e[0] = 0.0f;
#pragma unroll
            for (int j = 0; j < 4; ++j) {
                float cv = 0.0f;
                if (i + j < n) cv = sel_change(ann[i + j], c0, c1, c2, c3, c4);
                e[j + 1] = e[j] + cv;
            }
            e1 = e[1]; e2 = e[2]; e3 = e[3]; s = e[4];
        }

        // wave inclusive scan of per-thread sums
        float x = s;
#pragma unroll
        for (int off = 1; off < 64; off <<= 1) {
            float y = __shfl_up(x, off, 64);
            if (lane >= off) x += y;
        }
        if (lane == 63) wsum[t & 1][wv] = x;
        __syncthreads();
        float w0 = wsum[t & 1][0], w1 = wsum[t & 1][1];
        float w2 = wsum[t & 1][2], w3 = wsum[t & 1][3];
        float waveOff = (wv > 0 ? w0 : 0.0f) + (wv > 1 ? w1 : 0.0f) +
                        (wv > 2 ? w2 : 0.0f);
        float total = w0 + w1 + w2 + w3;
        // no 2nd barrier: next tile writes the OTHER wsum slot; this slot is
        // only rewritten after an intervening barrier (two tiles later).

        float b = running + waveOff + (x - s);  // exclusive prefix at i
        if (vec) {
            *reinterpret_cast<float4*>(out + i) =
                make_float4(b, b + e1, b + e2, b + e3);
        } else {
            if (i + 0 < n) out[i + 0] = b;
            if (i + 1 < n) out[i + 1] = b + e1;
            if (i + 2 < n) out[i + 2] = b + e2;
            if (i + 3 < n) out[i + 3] = b + e3;
        }
        running += total;
    }
    if (end == n && start < n && tid == 0) out[n] = running;
}

extern "C" void kernel_launch(void* const* d_in, const int* in_sizes, int n_in,
                              void* d_out, int out_size, void* d_ws, size_t ws_size,
                              hipStream_t stream) {
    const int* ann = (const int*)d_in[0];
    const float* org = (const float*)d_in[1];
    const float* bd = (const float*)d_in[2];
    const float* de = (const float*)d_in[3];
    const float* sa = (const float*)d_in[4];
    const float* in = (const float*)d_in[5];
    const float* bi = (const float*)d_in[6];
    float* out = (float*)d_out;

    long long n = (long long)in_sizes[0];
    int nb = (int)((n + CHUNK - 1) / CHUNK);  // 2048 for N=2^25
    if (nb < 1) nb = 1;

    int* bcT = (int*)d_ws;  // nb*5 ints, transposed [c][b]

    k_count<<<nb, THREADS, 0, stream>>>(ann, bcT, n, nb);
    k_emit<<<nb, THREADS, 0, stream>>>(ann, bcT, out, n, nb, org, bd, de, sa,
                                       in, bi);
}